// Round 1
// baseline (401.524 us; speedup 1.0000x reference)
//
#include <hip/hip_runtime.h>

// ---------------------------------------------------------------------------
// AbstractNN forward on MI355X.
// Outputs (f32, flat concat): x_out[14338][2048], x_min[2048], x_max[2048],
//                             x_true_out[32][2048].
// x_out rows: 0 = x@W.T+b (center), 1..8192 = eps@W.T, 8193..12288 = add_w
// (one-hot), 12289..14336 = add_b (one-hot), 14337 = noise@|W|.T.
// Strategy: bf16 MFMA GEMM (m97 structure) for the 8225-row dense part;
// memset+scatter for one-hot rows; column abs-sum for min/max.
// ---------------------------------------------------------------------------

typedef __bf16 bf16_t;
typedef bf16_t bf16x8 __attribute__((ext_vector_type(8)));
typedef float f32x4 __attribute__((ext_vector_type(4)));

#define D 2048
#define M_GEMM 8225              // 8193 (center+eps) + 32 (x_true)
#define ROW_ADDW 8193
#define ROW_ADDB 12289
#define ROW_NOISE 14337
#define N_OUT_ROWS 14338
#define OUT_MIN ((size_t)N_OUT_ROWS * D)   // 29364224
#define OUT_MAX (OUT_MIN + D)
#define OUT_XTRUE (OUT_MAX + D)            // 29368320
#define XB_ROWS 8320                       // 65 * 128 (pad rows read, not stored)
#define XB_BYTES ((size_t)XB_ROWS * D * 2)
#define WB_BYTES ((size_t)D * D * 2)

#define GLOAD_LDS16(g, l)                                                 \
  __builtin_amdgcn_global_load_lds(                                       \
      (__attribute__((address_space(1))) void*)(g),                       \
      (__attribute__((address_space(3))) void*)(l), 16, 0, 0)

// --------------------------- f32 -> bf16 convert ---------------------------
__global__ __launch_bounds__(256) void convert_x(const float* __restrict__ x,
                                                 const float* __restrict__ x_true,
                                                 bf16_t* __restrict__ Xb) {
  const int row = blockIdx.x;  // 0..8224
  const float* src = (row < 8193) ? (x + (size_t)row * D)
                                  : (x_true + (size_t)(row - 8193) * D);
  const int c = threadIdx.x * 8;
  float4 f0 = *(const float4*)(src + c);
  float4 f1 = *(const float4*)(src + c + 4);
  bf16x8 o;
  o[0] = (bf16_t)f0.x; o[1] = (bf16_t)f0.y; o[2] = (bf16_t)f0.z; o[3] = (bf16_t)f0.w;
  o[4] = (bf16_t)f1.x; o[5] = (bf16_t)f1.y; o[6] = (bf16_t)f1.z; o[7] = (bf16_t)f1.w;
  *(bf16x8*)(Xb + (size_t)row * D + c) = o;
}

__global__ __launch_bounds__(256) void convert_w(const float* __restrict__ W,
                                                 bf16_t* __restrict__ Wb) {
  const int row = blockIdx.x;  // 0..2047
  const float* src = W + (size_t)row * D;
  const int c = threadIdx.x * 8;
  float4 f0 = *(const float4*)(src + c);
  float4 f1 = *(const float4*)(src + c + 4);
  bf16x8 o;
  o[0] = (bf16_t)f0.x; o[1] = (bf16_t)f0.y; o[2] = (bf16_t)f0.z; o[3] = (bf16_t)f0.w;
  o[4] = (bf16_t)f1.x; o[5] = (bf16_t)f1.y; o[6] = (bf16_t)f1.z; o[7] = (bf16_t)f1.w;
  *(bf16x8*)(Wb + (size_t)row * D + c) = o;
}

// ------------------------------- bf16 GEMM ---------------------------------
// C[m][n] = sum_k Xb[m][k] * Wb[n][k]   (both operands K-contiguous)
// 128x128 tile, BK=64, 4 waves (2x2), each wave 64x64 = 4x4 MFMA fragments.
__global__ __launch_bounds__(256) void gemm_kernel(const bf16_t* __restrict__ Xb,
                                                   const bf16_t* __restrict__ Wb,
                                                   const float* __restrict__ bias,
                                                   float* __restrict__ out) {
  __shared__ bf16_t As[128 * 64];
  __shared__ bf16_t Bs[128 * 64];
  const int tid = threadIdx.x;
  const int w = tid >> 6;       // wave 0..3
  const int l = tid & 63;
  const int wr = w >> 1, wc = w & 1;
  const int m0 = blockIdx.y * 128;
  const int n0 = blockIdx.x * 128;
  const int g4 = l >> 4;        // 0..3
  const int r16 = l & 15;       // 0..15
  const int lrow = l >> 3;      // staging: 0..7
  const int lcol = (l & 7) * 8; // staging col (elements)

  f32x4 acc[4][4] = {};

  for (int kt = 0; kt < D / 64; ++kt) {
    const int k0 = kt * 64;
    // stage 32 KB via global_load_lds (wave-uniform LDS base + lane*16B)
    for (int i = 0; i < 8; ++i) {
      const int c = w * 8 + i;  // chunk 0..31, 1 KiB each
      if (c < 16) {
        const int row = c * 8 + lrow;
        const bf16_t* g = Xb + (size_t)(m0 + row) * D + k0 + lcol;
        GLOAD_LDS16(g, As + c * 512);
      } else {
        const int cc = c - 16;
        const int row = cc * 8 + lrow;
        const bf16_t* g = Wb + (size_t)(n0 + row) * D + k0 + lcol;
        GLOAD_LDS16(g, Bs + cc * 512);
      }
    }
    __syncthreads();
    for (int kk = 0; kk < 2; ++kk) {
      bf16x8 a[4], bb[4];
#pragma unroll
      for (int m = 0; m < 4; ++m)
        a[m] = *(const bf16x8*)&As[(wr * 64 + m * 16 + r16) * 64 + kk * 32 + g4 * 8];
#pragma unroll
      for (int n = 0; n < 4; ++n)
        bb[n] = *(const bf16x8*)&Bs[(wc * 64 + n * 16 + r16) * 64 + kk * 32 + g4 * 8];
#pragma unroll
      for (int m = 0; m < 4; ++m)
#pragma unroll
        for (int n = 0; n < 4; ++n)
          acc[m][n] = __builtin_amdgcn_mfma_f32_16x16x32_bf16(a[m], bb[n], acc[m][n], 0, 0, 0);
    }
    __syncthreads();
  }

  // epilogue: C/D layout col = l&15, row = (l>>4)*4 + j   [m89 verified]
#pragma unroll
  for (int m = 0; m < 4; ++m) {
    const int rbase = m0 + wr * 64 + m * 16 + g4 * 4;
#pragma unroll
    for (int n = 0; n < 4; ++n) {
      const int gc = n0 + wc * 64 + n * 16 + r16;
#pragma unroll
      for (int j = 0; j < 4; ++j) {
        const int gr = rbase + j;
        const float v = acc[m][n][j];
        if (gr == 0) {
          out[gc] = v + bias[gc];                       // x_value (+b)
        } else if (gr < 8193) {
          out[(size_t)gr * D + gc] = v;                 // x_eps (no bias)
        } else if (gr < M_GEMM) {
          out[OUT_XTRUE + (size_t)(gr - 8193) * D + gc] = v + bias[gc];  // x_true_out
        }
      }
    }
  }
}

// ------------------------------- scatter -----------------------------------
__global__ __launch_bounds__(256) void scatter_kernel(const float* __restrict__ x,
                                                      const float* __restrict__ w_val,
                                                      const float* __restrict__ b_val,
                                                      const int* __restrict__ w_idx,
                                                      const int* __restrict__ b_idx,
                                                      float* __restrict__ out) {
  const int i = blockIdx.x * 256 + threadIdx.x;
  if (i < 4096) {
    const int idx = w_idx[i];
    const int row = idx / D;     // out-feature
    const int col = idx % D;     // in-feature
    out[(size_t)(ROW_ADDW + i) * D + row] = w_val[i] * x[col];  // x[0] = center
  }
  const int ib = i - 4096;
  if (ib >= 0 && ib < 2048) {
    out[(size_t)(ROW_ADDB + ib) * D + b_idx[ib]] = b_val[ib];
  }
}

// ------------------------------- noise row ---------------------------------
__global__ __launch_bounds__(256) void noise_kernel(const float* __restrict__ x,
                                                    const float* __restrict__ W,
                                                    float* __restrict__ out) {
  __shared__ float red[4];
  const int tid = threadIdx.x;
  const int j = blockIdx.x;  // out column
  const float* wrow = W + (size_t)j * D;
  const float* xn = x + (size_t)8193 * D;  // noise input row
  float s = 0.f;
  for (int k = tid * 4; k < D; k += 1024) {
    float4 wv = *(const float4*)(wrow + k);
    float4 xv = *(const float4*)(xn + k);
    s += fabsf(wv.x) * xv.x + fabsf(wv.y) * xv.y + fabsf(wv.z) * xv.z + fabsf(wv.w) * xv.w;
  }
  for (int off = 32; off; off >>= 1) s += __shfl_down(s, off, 64);
  if ((tid & 63) == 0) red[tid >> 6] = s;
  __syncthreads();
  if (tid == 0) out[(size_t)ROW_NOISE * D + j] = red[0] + red[1] + red[2] + red[3];
}

// --------------------------- column abs-sum --------------------------------
__global__ __launch_bounds__(256) void abs_partial(const float* __restrict__ out,
                                                   float* __restrict__ partial) {
  const int col = blockIdx.x * 256 + threadIdx.x;  // 8 col-blocks
  const int rb = blockIdx.y;                       // 64 row-stripes
  float s = 0.f;
  for (int r = 1 + rb; r <= ROW_NOISE; r += 64)
    s += fabsf(out[(size_t)r * D + col]);
  partial[rb * D + col] = s;
}

__global__ __launch_bounds__(256) void final_minmax(const float* __restrict__ partial,
                                                    float* __restrict__ out) {
  const int col = blockIdx.x * 256 + threadIdx.x;
  float s = 0.f;
#pragma unroll 8
  for (int rb = 0; rb < 64; ++rb) s += partial[rb * D + col];
  const float c = out[col];  // x_value
  out[OUT_MIN + col] = c - s;
  out[OUT_MAX + col] = c + s;
}

// ------------------------------- launcher ----------------------------------
extern "C" void kernel_launch(void* const* d_in, const int* in_sizes, int n_in,
                              void* d_out, int out_size, void* d_ws, size_t ws_size,
                              hipStream_t stream) {
  const float* x      = (const float*)d_in[0];
  const float* x_true = (const float*)d_in[1];
  const float* W      = (const float*)d_in[2];
  const float* b      = (const float*)d_in[3];
  const float* w_val  = (const float*)d_in[4];
  const float* b_val  = (const float*)d_in[5];
  const int*   w_idx  = (const int*)d_in[6];
  const int*   b_idx  = (const int*)d_in[7];
  float* out = (float*)d_out;

  char* ws = (char*)d_ws;
  bf16_t* Xb = (bf16_t*)ws;                            // 8320*2048 bf16
  bf16_t* Wb = (bf16_t*)(ws + XB_BYTES);               // 2048*2048 bf16
  float* partial = (float*)(ws + XB_BYTES + WB_BYTES); // 64*2048 f32

  convert_x<<<dim3(M_GEMM), 256, 0, stream>>>(x, x_true, Xb);
  convert_w<<<dim3(D), 256, 0, stream>>>(W, Wb);
  // zero the one-hot region (rows 8193..14336 = 6144 rows)
  hipMemsetAsync(out + (size_t)ROW_ADDW * D, 0, (size_t)6144 * D * sizeof(float), stream);
  gemm_kernel<<<dim3(16, 65), 256, 0, stream>>>(Xb, Wb, b, out);
  scatter_kernel<<<dim3(24), 256, 0, stream>>>(x, w_val, b_val, w_idx, b_idx, out);
  noise_kernel<<<dim3(D), 256, 0, stream>>>(x, W, out);
  abs_partial<<<dim3(8, 64), 256, 0, stream>>>(out, partial);
  final_minmax<<<dim3(8), 256, 0, stream>>>(partial, out);
}

// Round 4
// 305.749 us; speedup vs baseline: 1.3132x; 1.3132x over previous
//
#include <hip/hip_runtime.h>

// ---------------------------------------------------------------------------
// AbstractNN forward on MI355X (gfx950).
// out (f32 flat): x_out[14338][2048], x_min[2048], x_max[2048], x_true_out[32][2048]
// x_out rows: 0=center@W.T+b, 1..8192=eps@W.T, 8193..12288=add_w, 12289..14336=add_b,
//             14337=noise@|W|.T
// GEMM: 256x256 8-phase bf16 MFMA template (T2 swizzle + T3/T4 counted vmcnt + T5),
//       M=8192 eps rows exactly -> 256 workgroups (1/CU). abs-sum fused in epilogue.
// 34 dense small rows (center, 32 x_true, noise) in an f32 dot kernel.
// ---------------------------------------------------------------------------

typedef __bf16 bf16_t;
typedef bf16_t bf16x8 __attribute__((ext_vector_type(8)));
typedef float f32x4 __attribute__((ext_vector_type(4)));

#define D 2048
#define NKT 32                   // K tiles of 64
#define ROW_ADDW 8193
#define ROW_ADDB 12289
#define ROW_NOISE 14337
#define N_OUT_ROWS 14338
#define OUT_MIN ((size_t)N_OUT_ROWS * D)
#define OUT_MAX (OUT_MIN + D)
#define OUT_XTRUE (OUT_MAX + D)

#define GLOAD_LDS16(g, l)                                                 \
  __builtin_amdgcn_global_load_lds(                                       \
      (__attribute__((address_space(1))) void*)(g),                       \
      (__attribute__((address_space(3))) void*)(l), 16, 0, 0)

// swizzled LDS fragment read: region element-ptr, row (0..255), c2 = col byte offset
#define LDSF(base, row, c2)                                               \
  (*(const bf16x8*)((const char*)(base) + (row) * 128 + ((c2) ^ (((row) & 7) << 4))))

// ------------------------- f32 -> bf16 converts ----------------------------
__global__ __launch_bounds__(256) void convert_eps(const float* __restrict__ x,
                                                   bf16_t* __restrict__ Xb) {
  const int row = blockIdx.x;            // 0..8191  -> x row (row+1)
  const int c = threadIdx.x * 8;
  const float* src = x + (size_t)(row + 1) * D + c;
  float4 f0 = *(const float4*)(src);
  float4 f1 = *(const float4*)(src + 4);
  bf16x8 o;
  o[0] = (bf16_t)f0.x; o[1] = (bf16_t)f0.y; o[2] = (bf16_t)f0.z; o[3] = (bf16_t)f0.w;
  o[4] = (bf16_t)f1.x; o[5] = (bf16_t)f1.y; o[6] = (bf16_t)f1.z; o[7] = (bf16_t)f1.w;
  *(bf16x8*)(Xb + (size_t)row * D + c) = o;
}

__global__ __launch_bounds__(256) void convert_w(const float* __restrict__ W,
                                                 bf16_t* __restrict__ Wb) {
  const int row = blockIdx.x;
  const int c = threadIdx.x * 8;
  const float* src = W + (size_t)row * D + c;
  float4 f0 = *(const float4*)(src);
  float4 f1 = *(const float4*)(src + 4);
  bf16x8 o;
  o[0] = (bf16_t)f0.x; o[1] = (bf16_t)f0.y; o[2] = (bf16_t)f0.z; o[3] = (bf16_t)f0.w;
  o[4] = (bf16_t)f1.x; o[5] = (bf16_t)f1.y; o[6] = (bf16_t)f1.z; o[7] = (bf16_t)f1.w;
  *(bf16x8*)(Wb + (size_t)row * D + c) = o;
}

// ----------------------- 256x256 8-phase bf16 GEMM -------------------------
// C[m][n] = sum_k Xb[m][k]*Wb[n][k]; writes out rows 1..8192 and per-block
// column |.| partials to gpart[(mt*2+wm)][col].
__global__ __launch_bounds__(512, 2) void gemm8_kernel(const bf16_t* __restrict__ Xb,
                                                       const bf16_t* __restrict__ Wb,
                                                       float* __restrict__ out,
                                                       float* __restrict__ gpart) {
  __shared__ bf16_t lds[65536];  // 128 KiB: buf{0,1} x (A[256][64], B[256][64])
  const int tid = threadIdx.x;
  const int wid = tid >> 6, l = tid & 63;
  const int wm = wid >> 2, wn = wid & 3;     // 2x4 waves
  const int g4 = l >> 4, r16 = l & 15;
  const int mt = blockIdx.y, nt = blockIdx.x;
  const int m0 = mt * 256, n0 = nt * 256;
  // staging decomposition: 512 threads, 16B each -> 8KB/issue (64 rows x 128B)
  const int sr = tid >> 3;                   // row within 64-row chunk
  const int scol = ((tid & 7) ^ (sr & 7)) << 3;  // pre-swizzled source col (elems)

  f32x4 acc[8][4] = {};

// stage one 128x64 half-tile (2 issues) from G rows [row0,row0+128) cols [k0,k0+64)
#define STAGE_HALF(G, row0, k0, ldsoff)                                          \
  {                                                                              \
    const bf16_t* _s0 = (G) + (size_t)((row0) + sr) * D + (k0) + scol;           \
    const bf16_t* _s1 = (G) + (size_t)((row0) + 64 + sr) * D + (k0) + scol;      \
    GLOAD_LDS16(_s0, &lds[(ldsoff) + tid * 8]);                                  \
    GLOAD_LDS16(_s1, &lds[(ldsoff) + 4096 + tid * 8]);                           \
  }

  // ---- prologue: tile0 (A+B -> buf0), tile1 B -> buf1 ----
  STAGE_HALF(Xb, m0, 0, 0);                 // A0.h0
  STAGE_HALF(Xb, m0 + 128, 0, 8192);        // A0.h1
  STAGE_HALF(Wb, n0, 0, 16384);             // B0.h0
  STAGE_HALF(Wb, n0 + 128, 0, 24576);       // B0.h1
  STAGE_HALF(Wb, n0, 64, 32768 + 16384);    // B1.h0
  STAGE_HALF(Wb, n0 + 128, 64, 32768 + 24576);  // B1.h1
  asm volatile("s_waitcnt vmcnt(4)" ::: "memory");  // A0+B0 landed; B1 in flight
  __builtin_amdgcn_sched_barrier(0);
  __builtin_amdgcn_s_barrier();
  __builtin_amdgcn_sched_barrier(0);

  for (int t = 0; t < NKT; ++t) {
    const int bufA = (t & 1) << 15;          // A(t) buffer (elements)
    const int bufN = ((t + 1) & 1) << 15;    // A(t+1) dest buffer
    const int k1 = (((t + 1) & (NKT - 1)) << 6);   // wrap-staged in epilogue (safe)
    const int k2 = (((t + 2) & (NKT - 1)) << 6);
    const bf16_t* Areg = &lds[bufA];
    const bf16_t* Breg = &lds[bufA + 16384];

    bf16x8 b[4][2];
    bf16x8 a[2][2];

#pragma unroll
    for (int q = 0; q < 4; ++q) {
      if (q == 0) {  // B fully consumed to regs in phase 1 (frees B region for q>=2 stages)
#pragma unroll
        for (int n = 0; n < 4; ++n)
#pragma unroll
          for (int kk = 0; kk < 2; ++kk)
            b[n][kk] = LDSF(Breg, wn * 64 + n * 16 + r16, kk * 64 + g4 * 16);
      }
#pragma unroll
      for (int f = 0; f < 2; ++f)
#pragma unroll
        for (int kk = 0; kk < 2; ++kk)
          a[f][kk] = LDSF(Areg, wm * 128 + q * 32 + f * 16 + r16, kk * 64 + g4 * 16);
      // stage schedule: A(t+1) halves at q=0,1 (into bufN, consumed last group);
      //                 B(t+2) halves at q=2,3 (into bufA.B, freed after q0)
      if (q == 0)      STAGE_HALF(Xb, m0,       k1, bufN)
      else if (q == 1) STAGE_HALF(Xb, m0 + 128, k1, bufN + 8192)
      else if (q == 2) STAGE_HALF(Wb, n0,       k2, bufA + 16384)
      else             STAGE_HALF(Wb, n0 + 128, k2, bufA + 24576)
      __builtin_amdgcn_sched_barrier(0);
      __builtin_amdgcn_s_barrier();
      __builtin_amdgcn_sched_barrier(0);
      __builtin_amdgcn_s_setprio(1);
#pragma unroll
      for (int f = 0; f < 2; ++f)
#pragma unroll
        for (int n = 0; n < 4; ++n)
#pragma unroll
          for (int kk = 0; kk < 2; ++kk)
            acc[q * 2 + f][n] = __builtin_amdgcn_mfma_f32_16x16x32_bf16(
                a[f][kk], b[n][kk], acc[q * 2 + f][n], 0, 0, 0);
      __builtin_amdgcn_s_setprio(0);
      __builtin_amdgcn_sched_barrier(0);
      if (q == 3) {  // counted vmcnt once per K-tile: keep B(t+2) (4 loads) in flight
        asm volatile("s_waitcnt vmcnt(4)" ::: "memory");
        __builtin_amdgcn_sched_barrier(0);
      }
      __builtin_amdgcn_s_barrier();
      __builtin_amdgcn_sched_barrier(0);
    }
  }

  // ---- epilogue: C write (out rows 1..8192) + per-column abs partials ----
#pragma unroll
  for (int m = 0; m < 8; ++m) {
    const int grow = m0 + wm * 128 + m * 16 + g4 * 4;
#pragma unroll
    for (int n = 0; n < 4; ++n) {
      const int gc = n0 + wn * 64 + n * 16 + r16;
#pragma unroll
      for (int j = 0; j < 4; ++j)
        out[(size_t)(grow + j + 1) * D + gc] = acc[m][n][j];
    }
  }
#pragma unroll
  for (int n = 0; n < 4; ++n) {
    float s = 0.f;
#pragma unroll
    for (int m = 0; m < 8; ++m)
#pragma unroll
      for (int j = 0; j < 4; ++j)
        s += fabsf(acc[m][n][j]);
    s += __shfl_xor(s, 16, 64);
    s += __shfl_xor(s, 32, 64);
    if (g4 == 0)
      gpart[(size_t)(mt * 2 + wm) * D + n0 + wn * 64 + n * 16 + r16] = s;
  }
#undef STAGE_HALF
}

// ------------------- 34 dense small rows (f32 exact) -----------------------
// rows: 0=center (x[0]), 1..32=x_true, 33=noise (x[8193] vs |W|)
__global__ __launch_bounds__(256) void smallrows_partial(const float* __restrict__ x,
                                                         const float* __restrict__ x_true,
                                                         const float* __restrict__ W,
                                                         float* __restrict__ spart) {
  const int j = blockIdx.x * 256 + threadIdx.x;  // out col
  const int kb = blockIdx.y;                     // 0..31, 64-wide K chunk
  const float* wrow = W + (size_t)j * D + kb * 64;
  const float* xc = x + kb * 64;
  const float* xn = x + (size_t)8193 * D + kb * 64;
  const float* xt = x_true + kb * 64;
  float acc[34];
#pragma unroll
  for (int r = 0; r < 34; ++r) acc[r] = 0.f;
  for (int k = 0; k < 64; k += 4) {
    float4 w = *(const float4*)(wrow + k);
    float4 v = *(const float4*)(xc + k);
    acc[0] += w.x * v.x + w.y * v.y + w.z * v.z + w.w * v.w;
#pragma unroll
    for (int r = 0; r < 32; ++r) {
      float4 u = *(const float4*)(xt + (size_t)r * D + k);
      acc[1 + r] += w.x * u.x + w.y * u.y + w.z * u.z + w.w * u.w;
    }
    float4 nn = *(const float4*)(xn + k);
    acc[33] += fabsf(w.x) * nn.x + fabsf(w.y) * nn.y + fabsf(w.z) * nn.z + fabsf(w.w) * nn.w;
  }
#pragma unroll
  for (int r = 0; r < 34; ++r)
    spart[((size_t)kb * 34 + r) * D + j] = acc[r];
}

__global__ __launch_bounds__(256) void smallrows_final(const float* __restrict__ spart,
                                                       const float* __restrict__ bias,
                                                       float* __restrict__ out) {
  const int j = blockIdx.x * 256 + threadIdx.x;
  const int r = blockIdx.y;  // 0..33
  float s = 0.f;
#pragma unroll 8
  for (int kb = 0; kb < 32; ++kb) s += spart[((size_t)kb * 34 + r) * D + j];
  if (r == 0)       out[j] = s + bias[j];
  else if (r <= 32) out[OUT_XTRUE + (size_t)(r - 1) * D + j] = s + bias[j];
  else              out[(size_t)ROW_NOISE * D + j] = s;
}

// ------------------------------- scatter -----------------------------------
__global__ __launch_bounds__(256) void scatter_kernel(const float* __restrict__ x,
                                                      const float* __restrict__ w_val,
                                                      const float* __restrict__ b_val,
                                                      const int* __restrict__ w_idx,
                                                      const int* __restrict__ b_idx,
                                                      float* __restrict__ out,
                                                      float* __restrict__ absacc) {
  const int i = blockIdx.x * 256 + threadIdx.x;
  if (i < 4096) {
    const int idx = w_idx[i];
    const int row = idx / D, col = idx % D;
    const float v = w_val[i] * x[col];
    out[(size_t)(ROW_ADDW + i) * D + row] = v;
    atomicAdd(&absacc[row], fabsf(v));
  }
  const int ib = i - 4096;
  if (ib >= 0 && ib < 2048) {
    const float v = b_val[ib];
    out[(size_t)(ROW_ADDB + ib) * D + b_idx[ib]] = v;
    atomicAdd(&absacc[b_idx[ib]], fabsf(v));
  }
}

// ------------------------------ min / max ----------------------------------
__global__ __launch_bounds__(256) void final_minmax(const float* __restrict__ gpart,
                                                    const float* __restrict__ absacc,
                                                    float* __restrict__ out) {
  const int col = blockIdx.x * 256 + threadIdx.x;
  float s = absacc[col];
#pragma unroll 8
  for (int p = 0; p < 64; ++p) s += gpart[(size_t)p * D + col];
  s += fabsf(out[(size_t)ROW_NOISE * D + col]);
  const float c = out[col];
  out[OUT_MIN + col] = c - s;
  out[OUT_MAX + col] = c + s;
}

// ------------------------------- launcher ----------------------------------
extern "C" void kernel_launch(void* const* d_in, const int* in_sizes, int n_in,
                              void* d_out, int out_size, void* d_ws, size_t ws_size,
                              hipStream_t stream) {
  const float* x      = (const float*)d_in[0];
  const float* x_true = (const float*)d_in[1];
  const float* W      = (const float*)d_in[2];
  const float* b      = (const float*)d_in[3];
  const float* w_val  = (const float*)d_in[4];
  const float* b_val  = (const float*)d_in[5];
  const int*   w_idx  = (const int*)d_in[6];
  const int*   b_idx  = (const int*)d_in[7];
  float* out = (float*)d_out;

  char* ws = (char*)d_ws;
  bf16_t* Xb    = (bf16_t*)ws;                         // 8192*2048*2 = 32 MiB
  bf16_t* Wb    = (bf16_t*)(ws + 33554432);            // 8 MiB
  float*  gpart = (float*)(ws + 41943040);             // 64*2048*4 = 512 KiB
  float*  spart = (float*)(ws + 42467328);             // 32*34*2048*4 = 8.5 MiB
  float*  absacc= (float*)(ws + 51380224);             // 2048*4

  // zero one-hot out rows (8193..14336) + scatter abs accumulator
  hipMemsetAsync(out + (size_t)ROW_ADDW * D, 0, (size_t)6144 * D * sizeof(float), stream);
  hipMemsetAsync(absacc, 0, D * sizeof(float), stream);

  convert_eps<<<dim3(8192), 256, 0, stream>>>(x, Xb);
  convert_w<<<dim3(D), 256, 0, stream>>>(W, Wb);
  gemm8_kernel<<<dim3(8, 32), 512, 0, stream>>>(Xb, Wb, out, gpart);
  smallrows_partial<<<dim3(8, 32), 256, 0, stream>>>(x, x_true, W, spart);
  smallrows_final<<<dim3(8, 34), 256, 0, stream>>>(spart, b, out);
  scatter_kernel<<<dim3(24), 256, 0, stream>>>(x, w_val, b_val, w_idx, b_idx, out, absacc);
  final_minmax<<<dim3(8), 256, 0, stream>>>(gpart, absacc, out);
}